// Round 19
// baseline (247.163 us; speedup 1.0000x reference)
//
#include <hip/hip_runtime.h>
#include <hip/hip_bf16.h>
#include <stdint.h>

// Capsule routing, f32 in/out. B=32, Nin=2048, Din=16, Nout=64, Dout=32, 3 iters.
// Round 19: R18 frozen (pass0 j-split + R11 IT skeleton) + ONE bit-exact delta:
// IT phase C reuses phase A's A-fragments (afr[4] carried in 16 VGPR across the
// two barriers) instead of re-loading Wh from L2 and re-deriving. Same MFMA,
// same operands -> identical numerics; removes 4 L2 loads/i/wave from phase C.

#define CB    32
#define NIN   2048
#define DIN   16
#define NOUT  64
#define DOUT  32
#define IPB   8
#define NCB   (NIN / IPB)            // 256
#define WI    (NOUT * DOUT * DIN)    // 32768 elements per i
#define WELEM ((size_t)NIN * WI)

typedef __attribute__((ext_vector_type(8)))  short bf16x8;
typedef __attribute__((ext_vector_type(16))) float f32x16;
typedef _Float16 h2 __attribute__((ext_vector_type(2)));

// IT LDS layout (bytes): [v 135168][c 8448][x 10240] = 153856
#define VOFF 0
#define COFF 135168
#define XOFF_IT 143616
#define SMEM_IT  153856

static __device__ __forceinline__ uint32_t pack_bf2(float a, float b) {
    __hip_bfloat162 hh = __float22bfloat162_rn(make_float2(a, b));
    uint32_t u; __builtin_memcpy(&u, &hh, 4); return u;
}
static __device__ __forceinline__ uint16_t f2bf(float v) {
    return (uint16_t)(pack_bf2(v, 0.f) & 0xffffu);
}
static __device__ __forceinline__ float bf2f(uint16_t u) {
    uint32_t v = (uint32_t)u << 16; float f; __builtin_memcpy(&f, &v, 4); return f;
}
static __device__ __forceinline__ uint32_t pack_h2(float a, float b) {
    h2 r; r.x = (_Float16)a; r.y = (_Float16)b;
    uint32_t u; __builtin_memcpy(&u, &r, 4); return u;
}
static __device__ __forceinline__ h2 as_h2(uint32_t u) {
    h2 r; __builtin_memcpy(&r, &u, 4); return r;
}

// ---------------- Pass 0: uniform coupling; j-half blocks; fused f32->bf16 transcode ----------------
// Block p: cb = p>>1, j-half = p&1. 8 waves; wave w owns j in [jh*32 + 4w, +4).
__global__ __launch_bounds__(512, 2) void caps_pass0(
    const float* __restrict__ x, const float* __restrict__ Wf,
    uint32_t* __restrict__ WhOut, uint16_t* __restrict__ s_partial)
{
    __shared__ uint32_t x_lds[IPB * 32 * 10];      // 10240 B

    const int p  = blockIdx.x;                     // 512 blocks
    const int cb = p >> 1, jh = p & 1;
    const int t  = threadIdx.x;
    const int w  = t >> 6, l = t & 63;
    const int bl = l & 31, h = l >> 5;
    const int j0 = jh * 32 + w * 4;

#pragma unroll
    for (int rep = 0; rep < 2; ++rep) {
        const int q = t + rep * 512;               // 0..1023
        const int b = q >> 5, i = (q >> 2) & 7, k4 = (q & 3) * 4;
        const float4 xv = *(const float4*)(x + ((size_t)b * NIN + cb * IPB + i) * DIN + k4);
        x_lds[(i * 32 + b) * 10 + (k4 >> 1)]     = pack_bf2(xv.x, xv.y);
        x_lds[(i * 32 + b) * 10 + (k4 >> 1) + 1] = pack_bf2(xv.z, xv.w);
    }
    __syncthreads();

    f32x16 sacc[4];
#pragma unroll
    for (int jj = 0; jj < 4; ++jj) sacc[jj] = (f32x16)0.0f;

#pragma unroll 1
    for (int i = 0; i < IPB; ++i) {
        const size_t wbase = (size_t)(cb * IPB + i) * WI;
        bf16x8 bfr;
        {
            uint32_t uu[4];
            const uint32_t* xp = &x_lds[(i * 32 + bl) * 10 + h * 4];
            uu[0] = xp[0]; uu[1] = xp[1]; uu[2] = xp[2]; uu[3] = xp[3];
            __builtin_memcpy(&bfr, uu, 16);
        }
#pragma unroll
        for (int jj = 0; jj < 4; ++jj) {
            const int j = j0 + jj;
            const size_t eoff = wbase + (size_t)(j * 32 + bl) * 16 + h * 8;
            const float4* wp = (const float4*)(Wf + eoff);
            const float4 a4 = wp[0], b4 = wp[1];
            uint32_t uu[4];
            uu[0] = pack_bf2(a4.x, a4.y); uu[1] = pack_bf2(a4.z, a4.w);
            uu[2] = pack_bf2(b4.x, b4.y); uu[3] = pack_bf2(b4.z, b4.w);
            bf16x8 afr; __builtin_memcpy(&afr, uu, 16);
            uint4 st; st.x = uu[0]; st.y = uu[1]; st.z = uu[2]; st.w = uu[3];
            *(uint4*)(WhOut + (eoff >> 1)) = st;
            sacc[jj] = __builtin_amdgcn_mfma_f32_32x32x16_bf16(afr, bfr, sacc[jj], 0, 0, 0);
        }
    }

#pragma unroll
    for (int jj = 0; jj < 4; ++jj) {
        const int j = j0 + jj;
#pragma unroll
        for (int r = 0; r < 16; ++r) {
            const int d = (r & 3) + 8 * (r >> 2) + 4 * h;
            s_partial[(size_t)cb * (2048 * 32) + (size_t)(j * 32 + d) * 32 + bl] =
                f2bf(sacc[jj][r] * (1.0f / 64.0f));
        }
    }
}

// ---------------- IT passes: R11 skeleton + afr register-carry A->C ----------------
template <int IT>
__global__ __launch_bounds__(1024, 4) void caps_it(
    const float* __restrict__ x, const uint16_t* __restrict__ Wb,
    const float* __restrict__ v_prev, const float* __restrict__ blog_in,
    float* __restrict__ blog_out, uint16_t* __restrict__ s_partial)
{
    extern __shared__ char smem[];
    uint32_t* v_lds = (uint32_t*)(smem + VOFF);      // [64j*16dp][33b] h2
    float*    c_lds = (float*)(smem + COFF);         // [64j][33b]
    uint32_t* x_lds = (uint32_t*)(smem + XOFF_IT);   // [8i*32b][10] k-pairs

    const int cb = blockIdx.x;
    const int t  = threadIdx.x;
    const int w  = t >> 6, l = t & 63;
    const int bl = l & 31, h = l >> 5;
    const int j0 = w * 4;

    {
        const int b = t >> 5, i = (t >> 2) & 7, k4 = (t & 3) * 4;
        const float4 xv = *(const float4*)(x + ((size_t)b * NIN + cb * IPB + i) * DIN + k4);
        x_lds[(i * 32 + b) * 10 + (k4 >> 1)]     = pack_bf2(xv.x, xv.y);
        x_lds[(i * 32 + b) * 10 + (k4 >> 1) + 1] = pack_bf2(xv.z, xv.w);
    }
#pragma unroll 4
    for (int rep = 0; rep < 32; ++rep) {
        const int idx = rep * 1024 + t;
        const int b = idx >> 10, j = (idx >> 4) & 63, dp = idx & 15;
        const float2 vv = *(const float2*)(v_prev + ((size_t)b * NOUT + j) * DOUT + dp * 2);
        v_lds[(j * 16 + dp) * 33 + b] = pack_h2(vv.x, vv.y);
    }
    __syncthreads();

    f32x16 sacc[4];
#pragma unroll
    for (int jj = 0; jj < 4; ++jj) sacc[jj] = (f32x16)0.0f;

    constexpr int base_dp[8] = {0, 1, 4, 5, 8, 9, 12, 13};

#pragma unroll 1
    for (int i = 0; i < IPB; ++i) {
        const int ig = cb * IPB + i;
        const size_t wbase = (size_t)ig * WI;

        bf16x8 bfr;
        {
            uint32_t uu[4];
            const uint32_t* xp = &x_lds[(i * 32 + bl) * 10 + h * 4];
            uu[0] = xp[0]; uu[1] = xp[1]; uu[2] = xp[2]; uu[3] = xp[3];
            __builtin_memcpy(&bfr, uu, 16);
        }

        // ===== PHASE A: logits for this wave's 4 j; afr[] kept for phase C =====
        bf16x8 afrs[4];
#pragma unroll
        for (int jj = 0; jj < 4; ++jj) {
            const int j = j0 + jj;
            afrs[jj] = *(const bf16x8*)(Wb + wbase + (size_t)(j * 32 + bl) * 16 + h * 8);
            const f32x16 D = __builtin_amdgcn_mfma_f32_32x32x16_bf16(afrs[jj], bfr, (f32x16)0.0f, 0, 0, 0);
            float acc = 0.f;
#pragma unroll
            for (int rp = 0; rp < 8; ++rp) {
                const int dp = base_dp[rp] + 2 * h;
                h2 dpk; dpk.x = (_Float16)D[2 * rp]; dpk.y = (_Float16)D[2 * rp + 1];
                acc = __builtin_amdgcn_fdot2(dpk, as_h2(v_lds[(j * 16 + dp) * 33 + bl]), acc, false);
            }
            acc += __shfl_xor(acc, 32);       // combine d-halves
            if (h == 0) c_lds[j * 33 + bl] = acc;
        }
        __syncthreads();

        // ===== PHASE B: softmax over j (32 b-rows, 2 per wave) =====
#pragma unroll
        for (int rr = 0; rr < 2; ++rr) {
            const int b = w * 2 + rr;
            float bv = c_lds[l * 33 + b];
            if (IT == 2) bv += blog_in[((size_t)b * NIN + ig) * NOUT + l];
            if (IT == 1) blog_out[((size_t)b * NIN + ig) * NOUT + l] = bv;
            float m = bv;
#pragma unroll
            for (int o = 32; o; o >>= 1) m = fmaxf(m, __shfl_xor(m, o));
            const float e = __expf(bv - m);
            float s = e;
#pragma unroll
            for (int o = 32; o; o >>= 1) s += __shfl_xor(s, o);
            c_lds[l * 33 + b] = e / s;
        }
        __syncthreads();

        // ===== PHASE C: accumulate (A-fragments reused from registers) =====
#pragma unroll
        for (int jj = 0; jj < 4; ++jj) {
            const int j = j0 + jj;
            const f32x16 D = __builtin_amdgcn_mfma_f32_32x32x16_bf16(afrs[jj], bfr, (f32x16)0.0f, 0, 0, 0);
            const float cv = c_lds[j * 33 + bl];      // c[b,i,j]: d-invariant
            sacc[jj] += D * cv;
        }
        __syncthreads();   // protect c_lds before next i's phase A
    }

    // ---- store partials: spart[cb][jd][b] bf16 ----
#pragma unroll
    for (int jj = 0; jj < 4; ++jj) {
        const int j = j0 + jj;
#pragma unroll
        for (int r = 0; r < 16; ++r) {
            const int d = (r & 3) + 8 * (r >> 2) + 4 * h;
            s_partial[(size_t)cb * (2048 * 32) + (size_t)(j * 32 + d) * 32 + bl] =
                f2bf(sacc[jj][r]);
        }
    }
}

// ---------------- reduce over cb + bias + squash (byte-identical) ----------------
__global__ __launch_bounds__(256) void caps_squash(
    const uint16_t* __restrict__ sp, const float* __restrict__ bias,
    float* __restrict__ vout)
{
    const int j  = blockIdx.x >> 2;
    const int bq = blockIdx.x & 3;
    const int t  = threadIdx.x;
    const int d  = t >> 3;
    const int blq = t & 7;
    const int b  = bq * 8 + blq;

    const uint16_t* p = sp + (size_t)(j * 32 + d) * 32 + b;
    float s0 = 0.f, s1 = 0.f, s2 = 0.f, s3 = 0.f;
#pragma unroll 4
    for (int c = 0; c < NCB; c += 4) {
        s0 += bf2f(p[(size_t)(c + 0) * (2048 * 32)]);
        s1 += bf2f(p[(size_t)(c + 1) * (2048 * 32)]);
        s2 += bf2f(p[(size_t)(c + 2) * (2048 * 32)]);
        s3 += bf2f(p[(size_t)(c + 3) * (2048 * 32)]);
    }
    const float sv = ((s0 + s1) + (s2 + s3)) + bias[j * DOUT + d];

    float sq = sv * sv;
    sq += __shfl_xor(sq, 8);
    sq += __shfl_xor(sq, 16);
    sq += __shfl_xor(sq, 32);

    __shared__ float sh[4][8];
    if ((t & 63) < 8) sh[t >> 6][t & 7] = sq;
    __syncthreads();
    const float tot = sh[0][blq] + sh[1][blq] + sh[2][blq] + sh[3][blq];
    const float scale = (tot / (1.0f + tot)) * rsqrtf(tot + 1e-9f);
    vout[(size_t)b * (NOUT * DOUT) + j * DOUT + d] = scale * sv;
}

extern "C" void kernel_launch(void* const* d_in, const int* in_sizes, int n_in,
                              void* d_out, int out_size, void* d_ws, size_t ws_size,
                              hipStream_t stream) {
    const float* x    = (const float*)d_in[0];
    const float* W    = (const float*)d_in[1];
    const float* bias = (const float*)d_in[2];
    float* out = (float*)d_out;

    // ws: Wh 134.22MB | blog 16.78MB | spart(bf16) 33.55MB | vbuf 0.26MB = 184.8MB
    char* base = (char*)d_ws;
    uint32_t* Wh    = (uint32_t*)base;
    float*    blog  = (float*)(base + WELEM * 2);
    uint16_t* spart = (uint16_t*)(base + WELEM * 2 + (size_t)CB * NIN * NOUT * 4);
    float*    vbuf  = (float*)(base + WELEM * 2 + (size_t)CB * NIN * NOUT * 4
                               + (size_t)NCB * 2048 * 32 * 2);
    (void)ws_size;

    hipFuncSetAttribute(reinterpret_cast<const void*>(caps_it<1>),
                        hipFuncAttributeMaxDynamicSharedMemorySize, SMEM_IT);
    hipFuncSetAttribute(reinterpret_cast<const void*>(caps_it<2>),
                        hipFuncAttributeMaxDynamicSharedMemorySize, SMEM_IT);

    caps_pass0<<<NCB * 2, 512, 0, stream>>>(x, W, Wh, spart);
    caps_squash<<<NOUT * 4, 256, 0, stream>>>(spart, bias, vbuf);

    caps_it<1><<<NCB, 1024, SMEM_IT, stream>>>(x, (const uint16_t*)Wh, vbuf, nullptr, blog, spart);
    caps_squash<<<NOUT * 4, 256, 0, stream>>>(spart, bias, vbuf);

    caps_it<2><<<NCB, 1024, SMEM_IT, stream>>>(x, (const uint16_t*)Wh, vbuf, blog, nullptr, spart);
    caps_squash<<<NOUT * 4, 256, 0, stream>>>(spart, bias, out);
}